// Round 7
// baseline (236.301 us; speedup 1.0000x reference)
//
#include <hip/hip_runtime.h>
#include <math.h>

#ifndef M_PI
#define M_PI 3.14159265358979323846
#endif

typedef _Float16 f16;
typedef _Float16 f16x8 __attribute__((ext_vector_type(8)));
typedef unsigned short u16x8 __attribute__((ext_vector_type(8)));
typedef float f32x4 __attribute__((ext_vector_type(4)));

#define NPHI 511
#define NM   255

// ---------------- K_leg: GL nodes (per-thread Newton) + legh + leghT + w64 --
__global__ __launch_bounds__(256) void k_leg(f16* __restrict__ legh, f16* __restrict__ leghT,
                                             double* __restrict__ w64) {
    __shared__ double c1[257], c2[257];
    __shared__ double sa[128], sb[128], sf[128];
    int m = blockIdx.x, t = threadIdx.x;
    for (int k = t; k <= 256; k += 256)
        if (k >= 2) { c1[k] = (2.0 * k - 1.0) / k; c2[k] = (k - 1.0) / k; }
    if (t < 128) {
        double dl = t, dm = m;
        if (t >= 2) {
            sa[t] = sqrt((4.0 * dl * dl - 1.0) / (dl * dl - dm * dm));
            sb[t] = sqrt(((dl - 1.0) * (dl - 1.0) - dm * dm) / (4.0 * (dl - 1.0) * (dl - 1.0) - 1.0));
        }
        if (t >= 1) sf[t] = -sqrt((2.0 * t + 1.0) / (2.0 * t));
    }
    __syncthreads();
    const int n = 256;
    double x = cos(M_PI * (t + 0.75) / (n + 0.5));
    double p1 = 0.0, pd = 1.0;
    for (int it = 0; it < 3; ++it) {
        double p0 = 1.0; p1 = x;
        for (int k = 2; k <= n; ++k) {
            double pk = c1[k] * x * p1 - c2[k] * p0;
            p0 = p1; p1 = pk;
        }
        pd = n * (x * p1 - p0) / (x * x - 1.0);
        x -= p1 / pd;
    }
    if (m == 0) w64[t] = 2.0 / ((1.0 - x * x) * pd * pd);
    double sx = sqrt(fmax(0.0, 1.0 - x * x));
    double pmm = 0.28209479177387814;   // 1/sqrt(4*pi)
    for (int k = 1; k <= m; ++k) pmm *= sf[k] * sx;
    double pm1 = (m + 1 < 128) ? sqrt(2.0 * m + 3.0) * x * pmm : 0.0;
    f16* Lm  = legh  + (size_t)m * 32768;
    f16* LmT = leghT + (size_t)m * 32768;
    double pprev = 0.0, pcur = 0.0;
    for (int l = 0; l < 128; ++l) {
        double v;
        if (l < m) v = 0.0;
        else if (l == m) v = pmm;
        else if (l == m + 1) v = pm1;
        else v = sa[l] * (x * pcur - sb[l] * pprev);
        if (l >= m) { pprev = pcur; pcur = v; }
        f16 h = (f16)v;
        Lm[l * 256 + t]  = h;
        LmT[t * 128 + l] = h;
    }
}

// ---------------- K_tables: CS[2][128][512], A5[512][512] -------------------
// A5 columns k=510,511 are EXACTLY ZERO -> G pad rows need no zeroing.
__global__ void k_tables_h(f16* __restrict__ CS, f16* __restrict__ A5) {
    int tid = blockIdx.x * blockDim.x + threadIdx.x;
    const float w0 = (float)(2.0 * M_PI / 511.0);
    if (tid < 128 * 512) {
        int m = tid >> 9, p = tid & 511;
        float cv = 0.f, sv = 0.f;
        if (p < 511) {
            int r = (p * m) % 511;
            float ang = w0 * (float)r;
            cv = cosf(ang) * w0;
            sv = -sinf(ang) * w0;
        }
        CS[tid] = (f16)cv; CS[65536 + tid] = (f16)sv;
    }
    {
        int p = tid >> 9, k = tid & 511;
        float v = 0.f;
        if (p < 511 && k < 510) {
            int mp = k >> 1, mmv = mp - 127;
            int r = (p * mmv) % 511; if (r < 0) r += 511;
            float ang = w0 * (float)r;
            v = (k & 1) ? -sinf(ang) : cosf(ang);
        }
        A5[tid] = (f16)v;
    }
}

// ---------------- K_prep_R: phi(l) reduce + Rph[l][co][ci] = R*phi ----------
__global__ __launch_bounds__(256) void k_prep_R(const float* __restrict__ Rr, const float* __restrict__ Ri,
        const float* __restrict__ Ar, const float* __restrict__ Ai, const float* __restrict__ te,
        f16* __restrict__ Rphr, f16* __restrict__ Rphi) {
    __shared__ float srd[256], sid[256];
    int l = blockIdx.x, tid = threadIdx.x;
    float tv = te[tid];
    srd[tid] = Ar[l * 256 + tid] * tv;
    sid[tid] = Ai[l * 256 + tid] * tv;
    __syncthreads();
    for (int s = 128; s > 0; s >>= 1) {
        if (tid < s) { srd[tid] += srd[tid + s]; sid[tid] += sid[tid + s]; }
        __syncthreads();
    }
    float phr = srd[0], phii = sid[0];
    const float* rr = Rr + (size_t)l * 4096;
    const float* ri = Ri + (size_t)l * 4096;
    #pragma unroll
    for (int e = 0; e < 2; ++e) {
        int base = tid * 8 + e * 2048;
        float4 r0 = *(const float4*)(rr + base), r1 = *(const float4*)(rr + base + 4);
        float4 q0 = *(const float4*)(ri + base), q1 = *(const float4*)(ri + base + 4);
        __align__(16) f16 hr[8], hi[8];
        hr[0] = (f16)(r0.x * phr - q0.x * phii); hi[0] = (f16)(r0.x * phii + q0.x * phr);
        hr[1] = (f16)(r0.y * phr - q0.y * phii); hi[1] = (f16)(r0.y * phii + q0.y * phr);
        hr[2] = (f16)(r0.z * phr - q0.z * phii); hi[2] = (f16)(r0.z * phii + q0.z * phr);
        hr[3] = (f16)(r0.w * phr - q0.w * phii); hi[3] = (f16)(r0.w * phii + q0.w * phr);
        hr[4] = (f16)(r1.x * phr - q1.x * phii); hi[4] = (f16)(r1.x * phii + q1.x * phr);
        hr[5] = (f16)(r1.y * phr - q1.y * phii); hi[5] = (f16)(r1.y * phii + q1.y * phr);
        hr[6] = (f16)(r1.z * phr - q1.z * phii); hi[6] = (f16)(r1.z * phii + q1.z * phr);
        hr[7] = (f16)(r1.w * phr - q1.w * phii); hi[7] = (f16)(r1.w * phii + q1.w * phr);
        *(float4*)(Rphr + (size_t)l * 4096 + base) = *(float4*)hr;
        *(float4*)(Rphi + (size_t)l * 4096 + base) = *(float4*)hi;
    }
}

// ---------------- K_convert: x[t][p][c] f32 -> xh[t][c][p(512)] f16 ---------
__global__ __launch_bounds__(256) void k_convert(const float* __restrict__ x, f16* __restrict__ xh) {
    __shared__ float Ls[64][68];
    int t = blockIdx.x, pt = blockIdx.y, tid = threadIdx.x;
    int p0 = pt * 64;
    const float* xb = x + (size_t)t * (NPHI * 64);
    #pragma unroll
    for (int e = 0; e < 4; ++e) {
        int idx = tid + e * 256;
        int row = idx >> 4, c4 = (idx & 15) * 4;
        int p = p0 + row;
        float4 v = make_float4(0.f, 0.f, 0.f, 0.f);
        if (p < NPHI) v = *(const float4*)(xb + (size_t)p * 64 + c4);
        *(float4*)&Ls[row][c4] = v;
    }
    __syncthreads();
    #pragma unroll
    for (int e = 0; e < 2; ++e) {
        int idx = tid + e * 256;
        int c = idx >> 3, r8 = (idx & 7) * 8;
        __align__(16) f16 tmp[8];
        #pragma unroll
        for (int j = 0; j < 8; ++j) tmp[j] = (f16)Ls[r8 + j][c];
        *(float4*)(xh + (size_t)t * 32768 + (size_t)c * 512 + p0 + r8) = *(float4*)tmp;
    }
}

// ---------------- generic fp16 transpose tile body --------------------------
__device__ __forceinline__ void tr16_body(const f16* __restrict__ s, f16* __restrict__ d,
                                          int R, int C, int rt, int ct, int tid) {
    __shared__ f16 Ts[64][72];
    const f16* sp = s + (size_t)(rt * 64) * C + ct * 64;
    #pragma unroll
    for (int e = 0; e < 2; ++e) {
        int idx = tid + e * 256;
        int row = idx >> 3, c8 = (idx & 7) * 8;
        *(float4*)&Ts[row][c8] = *(const float4*)(sp + (size_t)row * C + c8);
    }
    __syncthreads();
    f16* dp = d + (size_t)(ct * 64) * R + rt * 64;
    #pragma unroll
    for (int e = 0; e < 2; ++e) {
        int idx = tid + e * 256;
        int c = idx >> 3, r8 = (idx & 7) * 8;
        __align__(16) f16 tmp[8];
        #pragma unroll
        for (int j = 0; j < 8; ++j) tmp[j] = Ts[r8 + j][c];
        *(float4*)(dp + (size_t)c * R + r8) = *(float4*)tmp;
    }
}

__global__ __launch_bounds__(256) void k_tr16(const f16* __restrict__ src, f16* __restrict__ dst,
                                              int R, int C) {
    int b = blockIdx.x, tile = blockIdx.y, tid = threadIdx.x;
    int ctiles = C >> 6;
    int rt = tile / ctiles, ct = tile - rt * ctiles;
    tr16_body(src + (size_t)b * R * C, dst + (size_t)b * R * C, R, C, rt, ct, tid);
}

__global__ __launch_bounds__(256) void k_trp(const f16* __restrict__ s0, f16* __restrict__ d0,
                                             const f16* __restrict__ s1, f16* __restrict__ d1,
                                             int R, int C, int sstr, int dstr) {
    int b = blockIdx.x, tile = blockIdx.y, tid = threadIdx.x;
    int ctiles = C >> 6;
    int rt = tile / ctiles, ct = tile - rt * ctiles;
    const f16* s = ((blockIdx.z == 0) ? s0 : s1) + (size_t)b * sstr;
    f16*       d = ((blockIdx.z == 0) ? d0 : d1) + (size_t)b * dstr;
    tr16_body(s, d, R, C, rt, ct, tid);
}

// ---------------- K_g1: Fw[m][t][c] = w(t) * CS[half][m][p] . xh[t][c][p] ---
__global__ __launch_bounds__(256) void k_g1(const f16* __restrict__ xh, const f16* __restrict__ CS,
        const double* __restrict__ w64, f16* __restrict__ FwR, f16* __restrict__ FwI) {
    __shared__ __align__(16) f16 As[128][72], Bs[64][72];
    int t = blockIdx.x, half = blockIdx.y, tid = threadIdx.x;
    const f16* A = CS + (size_t)half * 65536;
    const f16* B = xh + (size_t)t * 32768;
    f32x4 acc[4][2];
    #pragma unroll
    for (int i = 0; i < 4; ++i)
        #pragma unroll
        for (int j = 0; j < 2; ++j) acc[i][j] = (f32x4){0.f, 0.f, 0.f, 0.f};
    int lane = tid & 63, wid = tid >> 6;
    int wm = wid & 1, wn = wid >> 1;
    int fr = lane & 15, g8 = (lane >> 4) * 8;
    for (int step = 0; step < 8; ++step) {
        float4 av[4], bv[2];
        #pragma unroll
        for (int e = 0; e < 4; ++e) {
            int idx = tid + e * 256;
            av[e] = *(const float4*)(A + (size_t)(idx >> 3) * 512 + step * 64 + (idx & 7) * 8);
        }
        #pragma unroll
        for (int e = 0; e < 2; ++e) {
            int idx = tid + e * 256;
            bv[e] = *(const float4*)(B + (size_t)(idx >> 3) * 512 + step * 64 + (idx & 7) * 8);
        }
        __syncthreads();
        #pragma unroll
        for (int e = 0; e < 4; ++e) {
            int idx = tid + e * 256;
            *(float4*)&As[idx >> 3][(idx & 7) * 8] = av[e];
        }
        #pragma unroll
        for (int e = 0; e < 2; ++e) {
            int idx = tid + e * 256;
            *(float4*)&Bs[idx >> 3][(idx & 7) * 8] = bv[e];
        }
        __syncthreads();
        #pragma unroll
        for (int ks = 0; ks < 2; ++ks) {
            int ko = ks * 32 + g8;
            f16x8 b0 = *(f16x8*)&Bs[wn * 32 + fr][ko];
            f16x8 b1 = *(f16x8*)&Bs[wn * 32 + 16 + fr][ko];
            #pragma unroll
            for (int mf = 0; mf < 4; ++mf) {
                f16x8 a = *(f16x8*)&As[wm * 64 + mf * 16 + fr][ko];
                acc[mf][0] = __builtin_amdgcn_mfma_f32_16x16x32_f16(a, b0, acc[mf][0], 0, 0, 0);
                acc[mf][1] = __builtin_amdgcn_mfma_f32_16x16x32_f16(a, b1, acc[mf][1], 0, 0, 0);
            }
        }
    }
    // LDS-staged epilogue: full 128B-row f16x8 stores (no partial-line RMW)
    float wf = (float)w64[t];
    f16* dst = half ? FwI : FwR;
    f16* stg = (f16*)&As[0][0];   // [32][72] f16 per chunk
    int rg = (lane >> 4) * 4;
    #pragma unroll 1
    for (int mf = 0; mf < 4; ++mf) {
        __syncthreads();
        #pragma unroll
        for (int nf = 0; nf < 2; ++nf)
            #pragma unroll
            for (int rr = 0; rr < 4; ++rr)
                stg[(wm * 16 + rg + rr) * 72 + wn * 32 + nf * 16 + fr] = (f16)(acc[mf][nf][rr] * wf);
        __syncthreads();
        int srow = tid >> 3, c8 = (tid & 7) * 8;
        int m = (srow >> 4) * 64 + mf * 16 + (srow & 15);
        *(float4*)(dst + (size_t)m * 16384 + t * 64 + c8) = *(float4*)&stg[srow * 72 + c8];
    }
}

// ---------------- K_g2: X[m][l][c] = legh[m][l][t] . FwT[m][u][c][t] --------
__global__ __launch_bounds__(256) void k_g2(const f16* __restrict__ legh, const f16* __restrict__ FwT,
        f16* __restrict__ Xhr, f16* __restrict__ Xhi) {
    __shared__ __align__(16) f16 As[64][72], Bs[128][72];
    int m = blockIdx.x, lt = blockIdx.y, tid = threadIdx.x;
    const f16* A = legh + (size_t)m * 32768 + (size_t)lt * 16384;
    const f16* B = FwT + (size_t)m * 32768;
    f32x4 acc[2][4];
    #pragma unroll
    for (int i = 0; i < 2; ++i)
        #pragma unroll
        for (int j = 0; j < 4; ++j) acc[i][j] = (f32x4){0.f, 0.f, 0.f, 0.f};
    int lane = tid & 63, wid = tid >> 6;
    int wm = wid & 1, wn = wid >> 1;
    int fr = lane & 15, g8 = (lane >> 4) * 8;
    for (int step = 0; step < 4; ++step) {
        float4 av[2], bv[4];
        #pragma unroll
        for (int e = 0; e < 2; ++e) {
            int idx = tid + e * 256;
            av[e] = *(const float4*)(A + (size_t)(idx >> 3) * 256 + step * 64 + (idx & 7) * 8);
        }
        #pragma unroll
        for (int e = 0; e < 4; ++e) {
            int idx = tid + e * 256;
            bv[e] = *(const float4*)(B + (size_t)(idx >> 3) * 256 + step * 64 + (idx & 7) * 8);
        }
        __syncthreads();
        #pragma unroll
        for (int e = 0; e < 2; ++e) {
            int idx = tid + e * 256;
            *(float4*)&As[idx >> 3][(idx & 7) * 8] = av[e];
        }
        #pragma unroll
        for (int e = 0; e < 4; ++e) {
            int idx = tid + e * 256;
            *(float4*)&Bs[idx >> 3][(idx & 7) * 8] = bv[e];
        }
        __syncthreads();
        #pragma unroll
        for (int ks = 0; ks < 2; ++ks) {
            int ko = ks * 32 + g8;
            f16x8 a0 = *(f16x8*)&As[wm * 32 + fr][ko];
            f16x8 a1 = *(f16x8*)&As[wm * 32 + 16 + fr][ko];
            #pragma unroll
            for (int nf = 0; nf < 4; ++nf) {
                f16x8 b = *(f16x8*)&Bs[wn * 64 + nf * 16 + fr][ko];
                acc[0][nf] = __builtin_amdgcn_mfma_f32_16x16x32_f16(a0, b, acc[0][nf], 0, 0, 0);
                acc[1][nf] = __builtin_amdgcn_mfma_f32_16x16x32_f16(a1, b, acc[1][nf], 0, 0, 0);
            }
        }
    }
    // LDS-staged epilogue
    f16* stg = (f16*)&As[0][0];   // [32][136] f16 (8704B <= 9216B)
    int rg = (lane >> 4) * 4;
    #pragma unroll 1
    for (int mf = 0; mf < 2; ++mf) {
        __syncthreads();
        #pragma unroll
        for (int nf = 0; nf < 4; ++nf)
            #pragma unroll
            for (int rr = 0; rr < 4; ++rr)
                stg[(wm * 16 + rg + rr) * 136 + wn * 64 + nf * 16 + fr] = (f16)acc[mf][nf][rr];
        __syncthreads();
        #pragma unroll
        for (int e = 0; e < 2; ++e) {
            int idx = tid + e * 256;
            int srow = idx >> 4, nn8 = (idx & 15) * 8;
            int l = lt * 64 + (srow >> 4) * 32 + mf * 16 + (srow & 15);
            f16* dp = (nn8 & 64) ? Xhi : Xhr;
            *(float4*)(dp + (size_t)m * 8192 + l * 64 + (nn8 & 63)) = *(float4*)&stg[srow * 136 + nn8];
        }
    }
}

// ---------------- K_s3m: Out[m'][co] = Xe[m'][ci] . Rph[co][ci] -------------
__global__ __launch_bounds__(256) void k_s3m(const f16* __restrict__ Xhr, const f16* __restrict__ Xhi,
        const f16* __restrict__ Rphr, const f16* __restrict__ Rphi,
        f16* __restrict__ Or, f16* __restrict__ Oi) {
    __shared__ f16 Ars[64][72], Ais[64][72], Ans[64][72];
    int l = blockIdx.x, mt = blockIdx.y, tid = threadIdx.x;
    {
        int arow = tid >> 2;
        int mp = mt * 64 + arow;
        int mmv = mp - 127, am = mmv < 0 ? -mmv : mmv;
        unsigned short cj = (mmv < 0) ? 0x8000 : 0;
        u16x8 cjv = {cj, cj, cj, cj, cj, cj, cj, cj};
        u16x8 ngv = {0x8000, 0x8000, 0x8000, 0x8000, 0x8000, 0x8000, 0x8000, 0x8000};
        #pragma unroll
        for (int e = 0; e < 2; ++e) {
            int ci8 = (tid & 3) * 8 + e * 32;
            u16x8 vr = {0, 0, 0, 0, 0, 0, 0, 0};
            u16x8 vi = {0, 0, 0, 0, 0, 0, 0, 0};
            if (mp < 255) {
                vr = *(const u16x8*)(Xhr + (size_t)am * 8192 + l * 64 + ci8);
                vi = *(const u16x8*)(Xhi + (size_t)am * 8192 + l * 64 + ci8);
            }
            u16x8 vic = vi ^ cjv;
            u16x8 vin = vic ^ ngv;
            *(u16x8*)&Ars[arow][ci8] = vr;
            *(u16x8*)&Ais[arow][ci8] = vic;
            *(u16x8*)&Ans[arow][ci8] = vin;
        }
    }
    __syncthreads();
    int lane = tid & 63, wid = tid >> 6;
    int wm = wid & 1, wn = wid >> 1;
    int fr = lane & 15, g8 = (lane >> 4) * 8;
    const f16* Bre = Rphr + (size_t)l * 4096;
    const f16* Bim = Rphi + (size_t)l * 4096;
    f32x4 accr[2][2], acci[2][2];
    #pragma unroll
    for (int a = 0; a < 2; ++a)
        #pragma unroll
        for (int b = 0; b < 2; ++b) { accr[a][b] = (f32x4){0.f,0.f,0.f,0.f}; acci[a][b] = (f32x4){0.f,0.f,0.f,0.f}; }
    #pragma unroll
    for (int ks = 0; ks < 2; ++ks) {
        int ko = ks * 32 + g8;
        f16x8 ar0 = *(f16x8*)&Ars[wm * 32 + fr][ko];
        f16x8 ar1 = *(f16x8*)&Ars[wm * 32 + 16 + fr][ko];
        f16x8 ai0 = *(f16x8*)&Ais[wm * 32 + fr][ko];
        f16x8 ai1 = *(f16x8*)&Ais[wm * 32 + 16 + fr][ko];
        f16x8 an0 = *(f16x8*)&Ans[wm * 32 + fr][ko];
        f16x8 an1 = *(f16x8*)&Ans[wm * 32 + 16 + fr][ko];
        #pragma unroll
        for (int nf = 0; nf < 2; ++nf) {
            int brow = wn * 32 + nf * 16 + fr;
            f16x8 br = *(const f16x8*)(Bre + (size_t)brow * 64 + ko);
            f16x8 bi = *(const f16x8*)(Bim + (size_t)brow * 64 + ko);
            accr[0][nf] = __builtin_amdgcn_mfma_f32_16x16x32_f16(ar0, br, accr[0][nf], 0, 0, 0);
            accr[0][nf] = __builtin_amdgcn_mfma_f32_16x16x32_f16(an0, bi, accr[0][nf], 0, 0, 0);
            acci[0][nf] = __builtin_amdgcn_mfma_f32_16x16x32_f16(ar0, bi, acci[0][nf], 0, 0, 0);
            acci[0][nf] = __builtin_amdgcn_mfma_f32_16x16x32_f16(ai0, br, acci[0][nf], 0, 0, 0);
            accr[1][nf] = __builtin_amdgcn_mfma_f32_16x16x32_f16(ar1, br, accr[1][nf], 0, 0, 0);
            accr[1][nf] = __builtin_amdgcn_mfma_f32_16x16x32_f16(an1, bi, accr[1][nf], 0, 0, 0);
            acci[1][nf] = __builtin_amdgcn_mfma_f32_16x16x32_f16(ar1, bi, acci[1][nf], 0, 0, 0);
            acci[1][nf] = __builtin_amdgcn_mfma_f32_16x16x32_f16(ai1, br, acci[1][nf], 0, 0, 0);
        }
    }
    // LDS-staged epilogue
    f16* stgR = (f16*)&Ars[0][0];  // [32][72]
    f16* stgI = (f16*)&Ais[0][0];  // [32][72]
    int rg = (lane >> 4) * 4;
    #pragma unroll 1
    for (int mf = 0; mf < 2; ++mf) {
        __syncthreads();
        #pragma unroll
        for (int nf = 0; nf < 2; ++nf)
            #pragma unroll
            for (int rr = 0; rr < 4; ++rr) {
                int si = (wm * 16 + rg + rr) * 72 + wn * 32 + nf * 16 + fr;
                stgR[si] = (f16)accr[mf][nf][rr];
                stgI[si] = (f16)acci[mf][nf][rr];
            }
        __syncthreads();
        int srow = tid >> 3, c8 = (tid & 7) * 8;
        int mp = mt * 64 + (srow >> 4) * 32 + mf * 16 + (srow & 15);
        if (mp < 255) {
            *(float4*)(Or + (size_t)mp * 8192 + l * 64 + c8) = *(float4*)&stgR[srow * 72 + c8];
            *(float4*)(Oi + (size_t)mp * 8192 + l * 64 + c8) = *(float4*)&stgI[srow * 72 + c8];
        }
    }
}

// ---------------- K_g4: G[2mp+u][t][c] = leghT[am][t][l] . OT[mp][u][c][l] --
__global__ __launch_bounds__(256) void k_g4(const f16* __restrict__ leghT, const f16* __restrict__ OT,
                                            f16* __restrict__ G) {
    __shared__ __align__(16) f16 As[128][72], Bs[128][72];
    int mp = blockIdx.x, th = blockIdx.y, tid = threadIdx.x;
    int mmv = mp - 127, am = mmv < 0 ? -mmv : mmv;
    const f16* A = leghT + (size_t)am * 32768 + (size_t)th * 16384;
    const f16* B = OT + (size_t)mp * 16384;
    f32x4 acc[4][4];
    #pragma unroll
    for (int i = 0; i < 4; ++i)
        #pragma unroll
        for (int j = 0; j < 4; ++j) acc[i][j] = (f32x4){0.f, 0.f, 0.f, 0.f};
    int lane = tid & 63, wid = tid >> 6;
    int wm = wid & 1, wn = wid >> 1;
    int fr = lane & 15, g8 = (lane >> 4) * 8;
    int nk0 = am >> 6;
    for (int step = nk0; step < 2; ++step) {
        float4 av[4], bv[4];
        #pragma unroll
        for (int e = 0; e < 4; ++e) {
            int idx = tid + e * 256;
            av[e] = *(const float4*)(A + (size_t)(idx >> 3) * 128 + step * 64 + (idx & 7) * 8);
            bv[e] = *(const float4*)(B + (size_t)(idx >> 3) * 128 + step * 64 + (idx & 7) * 8);
        }
        __syncthreads();
        #pragma unroll
        for (int e = 0; e < 4; ++e) {
            int idx = tid + e * 256;
            *(float4*)&As[idx >> 3][(idx & 7) * 8] = av[e];
            *(float4*)&Bs[idx >> 3][(idx & 7) * 8] = bv[e];
        }
        __syncthreads();
        #pragma unroll
        for (int ks = 0; ks < 2; ++ks) {
            int ko = ks * 32 + g8;
            f16x8 a[4];
            #pragma unroll
            for (int mf = 0; mf < 4; ++mf) a[mf] = *(f16x8*)&As[wm * 64 + mf * 16 + fr][ko];
            #pragma unroll
            for (int nf = 0; nf < 4; ++nf) {
                f16x8 b = *(f16x8*)&Bs[wn * 64 + nf * 16 + fr][ko];
                #pragma unroll
                for (int mf = 0; mf < 4; ++mf)
                    acc[mf][nf] = __builtin_amdgcn_mfma_f32_16x16x32_f16(a[mf], b, acc[mf][nf], 0, 0, 0);
            }
        }
    }
    // LDS-staged epilogue
    f16* stg = (f16*)&As[0][0];   // [32][136]
    int rg = (lane >> 4) * 4;
    #pragma unroll 1
    for (int mf = 0; mf < 4; ++mf) {
        __syncthreads();
        #pragma unroll
        for (int nf = 0; nf < 4; ++nf)
            #pragma unroll
            for (int rr = 0; rr < 4; ++rr)
                stg[(wm * 16 + rg + rr) * 136 + wn * 64 + nf * 16 + fr] = (f16)acc[mf][nf][rr];
        __syncthreads();
        #pragma unroll
        for (int e = 0; e < 2; ++e) {
            int idx = tid + e * 256;
            int srow = idx >> 4, nn8 = (idx & 15) * 8;
            int tg = th * 128 + (srow >> 4) * 64 + mf * 16 + (srow & 15);
            int u = nn8 >> 6;
            *(float4*)(G + (size_t)(2 * mp + u) * 16384 + tg * 64 + (nn8 & 63)) = *(float4*)&stg[srow * 136 + nn8];
        }
    }
}

// ---------------- K_g5: out[t][p][c] = A5[p][k] . GT[t][c][k] ---------------
__global__ __launch_bounds__(256) void k_g5(const f16* __restrict__ A5, const f16* __restrict__ GT,
                                            float* __restrict__ out) {
    __shared__ __align__(16) f16 As[128][72], Bs[64][72];
    int t = blockIdx.x, pt = blockIdx.y, tid = threadIdx.x;
    const f16* A = A5 + (size_t)pt * 65536;
    const f16* B = GT + (size_t)t * 32768;
    f32x4 acc[4][2];
    #pragma unroll
    for (int i = 0; i < 4; ++i)
        #pragma unroll
        for (int j = 0; j < 2; ++j) acc[i][j] = (f32x4){0.f, 0.f, 0.f, 0.f};
    int lane = tid & 63, wid = tid >> 6;
    int wm = wid & 1, wn = wid >> 1;
    int fr = lane & 15, g8 = (lane >> 4) * 8;
    for (int step = 0; step < 8; ++step) {
        float4 av[4], bv[2];
        #pragma unroll
        for (int e = 0; e < 4; ++e) {
            int idx = tid + e * 256;
            av[e] = *(const float4*)(A + (size_t)(idx >> 3) * 512 + step * 64 + (idx & 7) * 8);
        }
        #pragma unroll
        for (int e = 0; e < 2; ++e) {
            int idx = tid + e * 256;
            bv[e] = *(const float4*)(B + (size_t)(idx >> 3) * 512 + step * 64 + (idx & 7) * 8);
        }
        __syncthreads();
        #pragma unroll
        for (int e = 0; e < 4; ++e) {
            int idx = tid + e * 256;
            *(float4*)&As[idx >> 3][(idx & 7) * 8] = av[e];
        }
        #pragma unroll
        for (int e = 0; e < 2; ++e) {
            int idx = tid + e * 256;
            *(float4*)&Bs[idx >> 3][(idx & 7) * 8] = bv[e];
        }
        __syncthreads();
        #pragma unroll
        for (int ks = 0; ks < 2; ++ks) {
            int ko = ks * 32 + g8;
            f16x8 b0 = *(f16x8*)&Bs[wn * 32 + fr][ko];
            f16x8 b1 = *(f16x8*)&Bs[wn * 32 + 16 + fr][ko];
            #pragma unroll
            for (int mf = 0; mf < 4; ++mf) {
                f16x8 a = *(f16x8*)&As[wm * 64 + mf * 16 + fr][ko];
                acc[mf][0] = __builtin_amdgcn_mfma_f32_16x16x32_f16(a, b0, acc[mf][0], 0, 0, 0);
                acc[mf][1] = __builtin_amdgcn_mfma_f32_16x16x32_f16(a, b1, acc[mf][1], 0, 0, 0);
            }
        }
    }
    // LDS-staged epilogue: full 256B-row float4 stores (was 6.8x write-amplified)
    float* stg = (float*)&As[0][0];   // [32][68] f32 (8704B <= 18432B)
    int rg = (lane >> 4) * 4;
    #pragma unroll 1
    for (int mf = 0; mf < 4; ++mf) {
        __syncthreads();
        #pragma unroll
        for (int nf = 0; nf < 2; ++nf)
            #pragma unroll
            for (int rr = 0; rr < 4; ++rr)
                stg[(wm * 16 + rg + rr) * 68 + wn * 32 + nf * 16 + fr] = acc[mf][nf][rr];
        __syncthreads();
        #pragma unroll
        for (int e = 0; e < 2; ++e) {
            int idx = tid + e * 256;
            int srow = idx >> 4, c4 = (idx & 15) * 4;
            int p = pt * 128 + (srow >> 4) * 64 + mf * 16 + (srow & 15);
            if (p < NPHI)
                *(float4*)(out + ((size_t)t * NPHI + p) * 64 + c4) = *(float4*)&stg[srow * 68 + c4];
        }
    }
}

extern "C" void kernel_launch(void* const* d_in, const int* in_sizes, int n_in,
                              void* d_out, int out_size, void* d_ws, size_t ws_size,
                              hipStream_t stream) {
    const float* x    = (const float*)d_in[0];
    const float* temb = (const float*)d_in[1];
    const float* Ar   = (const float*)d_in[2];
    const float* Ai   = (const float*)d_in[3];
    const float* Rr   = (const float*)d_in[4];
    const float* Ri   = (const float*)d_in[5];
    float* out = (float*)d_out;

    char* ws = (char*)d_ws;
    size_t off = 0;
    auto alloc = [&](size_t bytes) -> void* {
        void* p = ws + off;
        off = (off + bytes + 255) & ~(size_t)255;
        return p;
    };
    double* w64  = (double*)alloc(256 * 8);
    f16* legh   = (f16*)alloc((size_t)128 * 128 * 256 * 2);   // 8.39 MB
    f16* leghT  = (f16*)alloc((size_t)128 * 256 * 128 * 2);   // 8.39 MB
    f16* CS     = (f16*)alloc((size_t)2 * 128 * 512 * 2);     // 256 KB
    f16* A5     = (f16*)alloc((size_t)512 * 512 * 2);         // 512 KB
    f16* Rphr   = (f16*)alloc((size_t)128 * 64 * 64 * 2);     // 1.05 MB
    f16* Rphi   = (f16*)alloc((size_t)128 * 64 * 64 * 2);
    f16* OT     = (f16*)alloc((size_t)255 * 2 * 64 * 128 * 2);// 8.36 MB
    f16* R1     = (f16*)alloc((size_t)256 * 64 * 512 * 2);    // 16.78 MB: xh -> Or/Oi -> GT
    f16* R2     = (f16*)alloc((size_t)512 * 256 * 64 * 2);    // 16.78 MB: FwR/FwI/FwT -> Xh -> Gk
    if (off > ws_size) return;

    f16* xh  = R1;
    f16* Or  = R1;
    f16* Oi  = R1 + (size_t)2097152;
    f16* GT  = R1;
    f16* FwR = R2;
    f16* FwI = R2 + (size_t)2097152;
    f16* FwT = R2 + (size_t)4194304;
    f16* Xhr = R2;
    f16* Xhi = R2 + (size_t)2097152;
    f16* Gk  = R2;   // rows 510,511 stale-but-finite; A5 cols 510,511 == 0

    hipLaunchKernelGGL(k_leg,      dim3(128),        dim3(256), 0, stream, legh, leghT, w64);
    hipLaunchKernelGGL(k_tables_h, dim3(1024),       dim3(256), 0, stream, CS, A5);
    hipLaunchKernelGGL(k_prep_R,   dim3(128),        dim3(256), 0, stream, Rr, Ri, Ar, Ai, temb, Rphr, Rphi);
    hipLaunchKernelGGL(k_convert,  dim3(256, 8),     dim3(256), 0, stream, x, xh);
    hipLaunchKernelGGL(k_g1,       dim3(256, 2),     dim3(256), 0, stream, xh, CS, w64, FwR, FwI);
    hipLaunchKernelGGL(k_trp,      dim3(128, 4, 2),  dim3(256), 0, stream, FwR, FwT, FwI, FwT + 16384, 256, 64, 16384, 32768);
    hipLaunchKernelGGL(k_g2,       dim3(128, 2),     dim3(256), 0, stream, legh, FwT, Xhr, Xhi);
    hipLaunchKernelGGL(k_s3m,      dim3(128, 4),     dim3(256), 0, stream, Xhr, Xhi, Rphr, Rphi, Or, Oi);
    hipLaunchKernelGGL(k_trp,      dim3(255, 2, 2),  dim3(256), 0, stream, Or, OT, Oi, OT + 8192, 128, 64, 2097152 / 256, 16384);
    hipLaunchKernelGGL(k_g4,       dim3(255, 2),     dim3(256), 0, stream, leghT, OT, Gk);
    hipLaunchKernelGGL(k_tr16,     dim3(1, 2048),    dim3(256), 0, stream, Gk, GT, 512, 16384);
    hipLaunchKernelGGL(k_g5,       dim3(256, 4),     dim3(256), 0, stream, A5, GT, out);
}

// Round 8
// 135.356 us; speedup vs baseline: 1.7458x; 1.7458x over previous
//
#include <hip/hip_runtime.h>
#include <math.h>

#ifndef M_PI
#define M_PI 3.14159265358979323846
#endif

typedef _Float16 f16;
typedef _Float16 f16x8 __attribute__((ext_vector_type(8)));
typedef unsigned short u16x8 __attribute__((ext_vector_type(8)));
typedef float f32x4 __attribute__((ext_vector_type(4)));

#define NPHI 511
#define NM   255

// ---------------- K_leg: GL nodes (per-thread Newton) + legh + leghT + w64 --
__global__ __launch_bounds__(256) void k_leg(f16* __restrict__ legh, f16* __restrict__ leghT,
                                             double* __restrict__ w64) {
    __shared__ double c1[257], c2[257];
    __shared__ double sa[128], sb[128], sf[128];
    int m = blockIdx.x, t = threadIdx.x;
    for (int k = t; k <= 256; k += 256)
        if (k >= 2) { c1[k] = (2.0 * k - 1.0) / k; c2[k] = (k - 1.0) / k; }
    if (t < 128) {
        double dl = t, dm = m;
        if (t >= 2) {
            sa[t] = sqrt((4.0 * dl * dl - 1.0) / (dl * dl - dm * dm));
            sb[t] = sqrt(((dl - 1.0) * (dl - 1.0) - dm * dm) / (4.0 * (dl - 1.0) * (dl - 1.0) - 1.0));
        }
        if (t >= 1) sf[t] = -sqrt((2.0 * t + 1.0) / (2.0 * t));
    }
    __syncthreads();
    const int n = 256;
    double x = cos(M_PI * (t + 0.75) / (n + 0.5));
    double p1 = 0.0, pd = 1.0;
    for (int it = 0; it < 3; ++it) {
        double p0 = 1.0; p1 = x;
        for (int k = 2; k <= n; ++k) {
            double pk = c1[k] * x * p1 - c2[k] * p0;
            p0 = p1; p1 = pk;
        }
        pd = n * (x * p1 - p0) / (x * x - 1.0);
        x -= p1 / pd;
    }
    if (m == 0) w64[t] = 2.0 / ((1.0 - x * x) * pd * pd);
    double sx = sqrt(fmax(0.0, 1.0 - x * x));
    double pmm = 0.28209479177387814;   // 1/sqrt(4*pi)
    for (int k = 1; k <= m; ++k) pmm *= sf[k] * sx;
    double pm1 = (m + 1 < 128) ? sqrt(2.0 * m + 3.0) * x * pmm : 0.0;
    f16* Lm  = legh  + (size_t)m * 32768;
    f16* LmT = leghT + (size_t)m * 32768;
    double pprev = 0.0, pcur = 0.0;
    for (int l = 0; l < 128; ++l) {
        double v;
        if (l < m) v = 0.0;
        else if (l == m) v = pmm;
        else if (l == m + 1) v = pm1;
        else v = sa[l] * (x * pcur - sb[l] * pprev);
        if (l >= m) { pprev = pcur; pcur = v; }
        f16 h = (f16)v;
        Lm[l * 256 + t]  = h;
        LmT[t * 128 + l] = h;
    }
}

// ---------------- K_tables: CS[2][128][512] (cos*s | -sin*s), A5[512][512] --
// A5 columns k=510,511 are EXACTLY ZERO -> G pad rows need no zeroing.
__global__ void k_tables_h(f16* __restrict__ CS, f16* __restrict__ A5) {
    int tid = blockIdx.x * blockDim.x + threadIdx.x;
    const float w0 = (float)(2.0 * M_PI / 511.0);
    if (tid < 128 * 512) {
        int m = tid >> 9, p = tid & 511;
        float cv = 0.f, sv = 0.f;
        if (p < 511) {
            int r = (p * m) % 511;
            float ang = w0 * (float)r;
            cv = cosf(ang) * w0;
            sv = -sinf(ang) * w0;
        }
        CS[tid] = (f16)cv; CS[65536 + tid] = (f16)sv;
    }
    {
        int p = tid >> 9, k = tid & 511;
        float v = 0.f;
        if (p < 511 && k < 510) {
            int mp = k >> 1, mmv = mp - 127;
            int r = (p * mmv) % 511; if (r < 0) r += 511;
            float ang = w0 * (float)r;
            v = (k & 1) ? -sinf(ang) : cosf(ang);
        }
        A5[tid] = (f16)v;
    }
}

// ---------------- K_prep_R: phi(l) reduce + Rph[l][co][ci] = R*phi ----------
__global__ __launch_bounds__(256) void k_prep_R(const float* __restrict__ Rr, const float* __restrict__ Ri,
        const float* __restrict__ Ar, const float* __restrict__ Ai, const float* __restrict__ te,
        f16* __restrict__ Rphr, f16* __restrict__ Rphi) {
    __shared__ float srd[256], sid[256];
    int l = blockIdx.x, tid = threadIdx.x;
    float tv = te[tid];
    srd[tid] = Ar[l * 256 + tid] * tv;
    sid[tid] = Ai[l * 256 + tid] * tv;
    __syncthreads();
    for (int s = 128; s > 0; s >>= 1) {
        if (tid < s) { srd[tid] += srd[tid + s]; sid[tid] += sid[tid + s]; }
        __syncthreads();
    }
    float phr = srd[0], phii = sid[0];
    const float* rr = Rr + (size_t)l * 4096;
    const float* ri = Ri + (size_t)l * 4096;
    #pragma unroll
    for (int e = 0; e < 2; ++e) {
        int base = tid * 8 + e * 2048;
        float4 r0 = *(const float4*)(rr + base), r1 = *(const float4*)(rr + base + 4);
        float4 q0 = *(const float4*)(ri + base), q1 = *(const float4*)(ri + base + 4);
        __align__(16) f16 hr[8], hi[8];
        hr[0] = (f16)(r0.x * phr - q0.x * phii); hi[0] = (f16)(r0.x * phii + q0.x * phr);
        hr[1] = (f16)(r0.y * phr - q0.y * phii); hi[1] = (f16)(r0.y * phii + q0.y * phr);
        hr[2] = (f16)(r0.z * phr - q0.z * phii); hi[2] = (f16)(r0.z * phii + q0.z * phr);
        hr[3] = (f16)(r0.w * phr - q0.w * phii); hi[3] = (f16)(r0.w * phii + q0.w * phr);
        hr[4] = (f16)(r1.x * phr - q1.x * phii); hi[4] = (f16)(r1.x * phii + q1.x * phr);
        hr[5] = (f16)(r1.y * phr - q1.y * phii); hi[5] = (f16)(r1.y * phii + q1.y * phr);
        hr[6] = (f16)(r1.z * phr - q1.z * phii); hi[6] = (f16)(r1.z * phii + q1.z * phr);
        hr[7] = (f16)(r1.w * phr - q1.w * phii); hi[7] = (f16)(r1.w * phii + q1.w * phr);
        *(float4*)(Rphr + (size_t)l * 4096 + base) = *(float4*)hr;
        *(float4*)(Rphi + (size_t)l * 4096 + base) = *(float4*)hi;
    }
}

// ---------------- K_convert: x[t][p][c] f32 -> xh[t][c][p(512)] f16 ---------
__global__ __launch_bounds__(256) void k_convert(const float* __restrict__ x, f16* __restrict__ xh) {
    __shared__ float Ls[64][68];
    int t = blockIdx.x, pt = blockIdx.y, tid = threadIdx.x;
    int p0 = pt * 64;
    const float* xb = x + (size_t)t * (NPHI * 64);
    #pragma unroll
    for (int e = 0; e < 4; ++e) {
        int idx = tid + e * 256;
        int row = idx >> 4, c4 = (idx & 15) * 4;
        int p = p0 + row;
        float4 v = make_float4(0.f, 0.f, 0.f, 0.f);
        if (p < NPHI) v = *(const float4*)(xb + (size_t)p * 64 + c4);
        *(float4*)&Ls[row][c4] = v;
    }
    __syncthreads();
    #pragma unroll
    for (int e = 0; e < 2; ++e) {
        int idx = tid + e * 256;
        int c = idx >> 3, r8 = (idx & 7) * 8;
        __align__(16) f16 tmp[8];
        #pragma unroll
        for (int j = 0; j < 8; ++j) tmp[j] = (f16)Ls[r8 + j][c];
        *(float4*)(xh + (size_t)t * 32768 + (size_t)c * 512 + p0 + r8) = *(float4*)tmp;
    }
}

// ---------------- generic fp16 transpose tile body --------------------------
__device__ __forceinline__ void tr16_body(const f16* __restrict__ s, f16* __restrict__ d,
                                          int R, int C, int rt, int ct, int tid) {
    __shared__ f16 Ts[64][72];
    const f16* sp = s + (size_t)(rt * 64) * C + ct * 64;
    #pragma unroll
    for (int e = 0; e < 2; ++e) {
        int idx = tid + e * 256;
        int row = idx >> 3, c8 = (idx & 7) * 8;
        *(float4*)&Ts[row][c8] = *(const float4*)(sp + (size_t)row * C + c8);
    }
    __syncthreads();
    f16* dp = d + (size_t)(ct * 64) * R + rt * 64;
    #pragma unroll
    for (int e = 0; e < 2; ++e) {
        int idx = tid + e * 256;
        int c = idx >> 3, r8 = (idx & 7) * 8;
        __align__(16) f16 tmp[8];
        #pragma unroll
        for (int j = 0; j < 8; ++j) tmp[j] = Ts[r8 + j][c];
        *(float4*)(dp + (size_t)c * R + r8) = *(float4*)tmp;
    }
}

__global__ __launch_bounds__(256) void k_tr16(const f16* __restrict__ src, f16* __restrict__ dst,
                                              int R, int C) {
    int b = blockIdx.x, tile = blockIdx.y, tid = threadIdx.x;
    int ctiles = C >> 6;
    int rt = tile / ctiles, ct = tile - rt * ctiles;
    tr16_body(src + (size_t)b * R * C, dst + (size_t)b * R * C, R, C, rt, ct, tid);
}

__global__ __launch_bounds__(256) void k_trp(const f16* __restrict__ s0, f16* __restrict__ d0,
                                             const f16* __restrict__ s1, f16* __restrict__ d1,
                                             int R, int C, int sstr, int dstr) {
    int b = blockIdx.x, tile = blockIdx.y, tid = threadIdx.x;
    int ctiles = C >> 6;
    int rt = tile / ctiles, ct = tile - rt * ctiles;
    const f16* s = ((blockIdx.z == 0) ? s0 : s1) + (size_t)b * sstr;
    f16*       d = ((blockIdx.z == 0) ? d0 : d1) + (size_t)b * dstr;
    tr16_body(s, d, R, C, rt, ct, tid);
}

// ---------------- K_g1: stage 1 MFMA (64-tile, round-4 form) ----------------
__global__ __launch_bounds__(256) void k_g1(const f16* __restrict__ xh, const f16* __restrict__ cF,
        const f16* __restrict__ sF, const double* __restrict__ w64,
        f16* __restrict__ FwR, f16* __restrict__ FwI) {
    __shared__ f16 Ac[64][40], An[64][40], Bs[64][40];
    int t = blockIdx.x, mt = blockIdx.y, tid = threadIdx.x;
    const f16* A0 = cF + (size_t)(mt * 64) * 512;
    const f16* A1 = sF + (size_t)(mt * 64) * 512;
    const f16* B  = xh + (size_t)t * (64 * 512);
    f32x4 acc[2][2][2];  // [tab][mf][nf]
    #pragma unroll
    for (int a = 0; a < 2; ++a)
        #pragma unroll
        for (int b = 0; b < 2; ++b)
            #pragma unroll
            for (int c = 0; c < 2; ++c) acc[a][b][c] = (f32x4){0.f, 0.f, 0.f, 0.f};
    int lane = tid & 63, wid = tid >> 6;
    int wm = wid & 1, wn = wid >> 1;
    int fr = lane & 15, g8 = (lane >> 4) * 8;
    int row = tid >> 2, k8 = (tid & 3) * 8;
    for (int kt = 0; kt < 16; ++kt) {
        float4 va = *(const float4*)(A0 + (size_t)row * 512 + kt * 32 + k8);
        float4 vn = *(const float4*)(A1 + (size_t)row * 512 + kt * 32 + k8);
        float4 vb = *(const float4*)(B  + (size_t)row * 512 + kt * 32 + k8);
        __syncthreads();
        *(float4*)&Ac[row][k8] = va;
        *(float4*)&An[row][k8] = vn;
        *(float4*)&Bs[row][k8] = vb;
        __syncthreads();
        f16x8 b0 = *(f16x8*)&Bs[wn * 32 + fr][g8];
        f16x8 b1 = *(f16x8*)&Bs[wn * 32 + 16 + fr][g8];
        f16x8 a0 = *(f16x8*)&Ac[wm * 32 + fr][g8];
        f16x8 a1 = *(f16x8*)&Ac[wm * 32 + 16 + fr][g8];
        f16x8 s0 = *(f16x8*)&An[wm * 32 + fr][g8];
        f16x8 s1 = *(f16x8*)&An[wm * 32 + 16 + fr][g8];
        acc[0][0][0] = __builtin_amdgcn_mfma_f32_16x16x32_f16(a0, b0, acc[0][0][0], 0, 0, 0);
        acc[0][0][1] = __builtin_amdgcn_mfma_f32_16x16x32_f16(a0, b1, acc[0][0][1], 0, 0, 0);
        acc[0][1][0] = __builtin_amdgcn_mfma_f32_16x16x32_f16(a1, b0, acc[0][1][0], 0, 0, 0);
        acc[0][1][1] = __builtin_amdgcn_mfma_f32_16x16x32_f16(a1, b1, acc[0][1][1], 0, 0, 0);
        acc[1][0][0] = __builtin_amdgcn_mfma_f32_16x16x32_f16(s0, b0, acc[1][0][0], 0, 0, 0);
        acc[1][0][1] = __builtin_amdgcn_mfma_f32_16x16x32_f16(s0, b1, acc[1][0][1], 0, 0, 0);
        acc[1][1][0] = __builtin_amdgcn_mfma_f32_16x16x32_f16(s1, b0, acc[1][1][0], 0, 0, 0);
        acc[1][1][1] = __builtin_amdgcn_mfma_f32_16x16x32_f16(s1, b1, acc[1][1][1], 0, 0, 0);
    }
    float wf = (float)w64[t];
    int rg = (lane >> 4) * 4;
    #pragma unroll
    for (int mf = 0; mf < 2; ++mf)
        #pragma unroll
        for (int nf = 0; nf < 2; ++nf) {
            int c = wn * 32 + nf * 16 + fr;
            #pragma unroll
            for (int r = 0; r < 4; ++r) {
                int m = mt * 64 + wm * 32 + mf * 16 + rg + r;
                FwR[((size_t)m * 256 + t) * 64 + c] = (f16)(acc[0][mf][nf][r] * wf);
                FwI[((size_t)m * 256 + t) * 64 + c] = (f16)(acc[1][mf][nf][r] * wf);
            }
        }
}

// ---------------- K_g2: stage 2 MFMA (64-tile, round-4 form) ----------------
__global__ __launch_bounds__(256) void k_g2(const f16* __restrict__ legh, const f16* __restrict__ BTr,
        const f16* __restrict__ BTi, f16* __restrict__ Xhr, f16* __restrict__ Xhi) {
    __shared__ f16 As[64][40], Br[64][40], Bi[64][40];
    int m = blockIdx.x, lt = blockIdx.y, tid = threadIdx.x;
    const f16* A  = legh + (size_t)m * (128 * 256) + (size_t)(lt * 64) * 256;
    const f16* B0 = BTr + (size_t)m * (64 * 256);
    const f16* B1 = BTi + (size_t)m * (64 * 256);
    f32x4 acc[2][2][2];  // [bsel][mf][nf]
    #pragma unroll
    for (int a = 0; a < 2; ++a)
        #pragma unroll
        for (int b = 0; b < 2; ++b)
            #pragma unroll
            for (int c = 0; c < 2; ++c) acc[a][b][c] = (f32x4){0.f, 0.f, 0.f, 0.f};
    int lane = tid & 63, wid = tid >> 6;
    int wm = wid & 1, wn = wid >> 1;
    int fr = lane & 15, g8 = (lane >> 4) * 8;
    int row = tid >> 2, k8 = (tid & 3) * 8;
    for (int kt = 0; kt < 8; ++kt) {
        float4 va = *(const float4*)(A  + (size_t)row * 256 + kt * 32 + k8);
        float4 vr = *(const float4*)(B0 + (size_t)row * 256 + kt * 32 + k8);
        float4 vi = *(const float4*)(B1 + (size_t)row * 256 + kt * 32 + k8);
        __syncthreads();
        *(float4*)&As[row][k8] = va;
        *(float4*)&Br[row][k8] = vr;
        *(float4*)&Bi[row][k8] = vi;
        __syncthreads();
        f16x8 a0 = *(f16x8*)&As[wm * 32 + fr][g8];
        f16x8 a1 = *(f16x8*)&As[wm * 32 + 16 + fr][g8];
        f16x8 r0 = *(f16x8*)&Br[wn * 32 + fr][g8];
        f16x8 r1 = *(f16x8*)&Br[wn * 32 + 16 + fr][g8];
        f16x8 i0 = *(f16x8*)&Bi[wn * 32 + fr][g8];
        f16x8 i1 = *(f16x8*)&Bi[wn * 32 + 16 + fr][g8];
        acc[0][0][0] = __builtin_amdgcn_mfma_f32_16x16x32_f16(a0, r0, acc[0][0][0], 0, 0, 0);
        acc[0][0][1] = __builtin_amdgcn_mfma_f32_16x16x32_f16(a0, r1, acc[0][0][1], 0, 0, 0);
        acc[0][1][0] = __builtin_amdgcn_mfma_f32_16x16x32_f16(a1, r0, acc[0][1][0], 0, 0, 0);
        acc[0][1][1] = __builtin_amdgcn_mfma_f32_16x16x32_f16(a1, r1, acc[0][1][1], 0, 0, 0);
        acc[1][0][0] = __builtin_amdgcn_mfma_f32_16x16x32_f16(a0, i0, acc[1][0][0], 0, 0, 0);
        acc[1][0][1] = __builtin_amdgcn_mfma_f32_16x16x32_f16(a0, i1, acc[1][0][1], 0, 0, 0);
        acc[1][1][0] = __builtin_amdgcn_mfma_f32_16x16x32_f16(a1, i0, acc[1][1][0], 0, 0, 0);
        acc[1][1][1] = __builtin_amdgcn_mfma_f32_16x16x32_f16(a1, i1, acc[1][1][1], 0, 0, 0);
    }
    int rg = (lane >> 4) * 4;
    #pragma unroll
    for (int mf = 0; mf < 2; ++mf)
        #pragma unroll
        for (int nf = 0; nf < 2; ++nf) {
            int c = wn * 32 + nf * 16 + fr;
            #pragma unroll
            for (int r = 0; r < 4; ++r) {
                int l = lt * 64 + wm * 32 + mf * 16 + rg + r;
                Xhr[(size_t)m * 8192 + l * 64 + c] = (f16)acc[0][mf][nf][r];
                Xhi[(size_t)m * 8192 + l * 64 + c] = (f16)acc[1][mf][nf][r];
            }
        }
}

// ---------------- K_s3m: stage 3 MFMA (round-4 form) ------------------------
__global__ __launch_bounds__(256) void k_s3m(const f16* __restrict__ Xhr, const f16* __restrict__ Xhi,
        const f16* __restrict__ Rphr, const f16* __restrict__ Rphi,
        f16* __restrict__ Or, f16* __restrict__ Oi) {
    __shared__ f16 Ars[64][72], Ais[64][72], Ans[64][72];
    int l = blockIdx.x, mt = blockIdx.y, tid = threadIdx.x;
    {
        int arow = tid >> 2;
        int mp = mt * 64 + arow;
        int mmv = mp - 127, am = mmv < 0 ? -mmv : mmv;
        unsigned short cj = (mmv < 0) ? 0x8000 : 0;
        u16x8 cjv = {cj, cj, cj, cj, cj, cj, cj, cj};
        u16x8 ngv = {0x8000, 0x8000, 0x8000, 0x8000, 0x8000, 0x8000, 0x8000, 0x8000};
        #pragma unroll
        for (int e = 0; e < 2; ++e) {
            int ci8 = (tid & 3) * 8 + e * 32;
            u16x8 vr = {0, 0, 0, 0, 0, 0, 0, 0};
            u16x8 vi = {0, 0, 0, 0, 0, 0, 0, 0};
            if (mp < 255) {
                vr = *(const u16x8*)(Xhr + (size_t)am * 8192 + l * 64 + ci8);
                vi = *(const u16x8*)(Xhi + (size_t)am * 8192 + l * 64 + ci8);
            }
            u16x8 vic = vi ^ cjv;
            u16x8 vin = vic ^ ngv;
            *(u16x8*)&Ars[arow][ci8] = vr;
            *(u16x8*)&Ais[arow][ci8] = vic;
            *(u16x8*)&Ans[arow][ci8] = vin;
        }
    }
    __syncthreads();
    int lane = tid & 63, wid = tid >> 6;
    int wm = wid & 1, wn = wid >> 1;
    int fr = lane & 15, g8 = (lane >> 4) * 8;
    const f16* Bre = Rphr + (size_t)l * 4096;
    const f16* Bim = Rphi + (size_t)l * 4096;
    f32x4 accr[2][2], acci[2][2];
    #pragma unroll
    for (int a = 0; a < 2; ++a)
        #pragma unroll
        for (int b = 0; b < 2; ++b) { accr[a][b] = (f32x4){0.f,0.f,0.f,0.f}; acci[a][b] = (f32x4){0.f,0.f,0.f,0.f}; }
    #pragma unroll
    for (int ks = 0; ks < 2; ++ks) {
        int ko = ks * 32 + g8;
        f16x8 ar0 = *(f16x8*)&Ars[wm * 32 + fr][ko];
        f16x8 ar1 = *(f16x8*)&Ars[wm * 32 + 16 + fr][ko];
        f16x8 ai0 = *(f16x8*)&Ais[wm * 32 + fr][ko];
        f16x8 ai1 = *(f16x8*)&Ais[wm * 32 + 16 + fr][ko];
        f16x8 an0 = *(f16x8*)&Ans[wm * 32 + fr][ko];
        f16x8 an1 = *(f16x8*)&Ans[wm * 32 + 16 + fr][ko];
        #pragma unroll
        for (int nf = 0; nf < 2; ++nf) {
            int brow = wn * 32 + nf * 16 + fr;
            f16x8 br = *(const f16x8*)(Bre + (size_t)brow * 64 + ko);
            f16x8 bi = *(const f16x8*)(Bim + (size_t)brow * 64 + ko);
            accr[0][nf] = __builtin_amdgcn_mfma_f32_16x16x32_f16(ar0, br, accr[0][nf], 0, 0, 0);
            accr[0][nf] = __builtin_amdgcn_mfma_f32_16x16x32_f16(an0, bi, accr[0][nf], 0, 0, 0);
            acci[0][nf] = __builtin_amdgcn_mfma_f32_16x16x32_f16(ar0, bi, acci[0][nf], 0, 0, 0);
            acci[0][nf] = __builtin_amdgcn_mfma_f32_16x16x32_f16(ai0, br, acci[0][nf], 0, 0, 0);
            accr[1][nf] = __builtin_amdgcn_mfma_f32_16x16x32_f16(ar1, br, accr[1][nf], 0, 0, 0);
            accr[1][nf] = __builtin_amdgcn_mfma_f32_16x16x32_f16(an1, bi, accr[1][nf], 0, 0, 0);
            acci[1][nf] = __builtin_amdgcn_mfma_f32_16x16x32_f16(ar1, bi, acci[1][nf], 0, 0, 0);
            acci[1][nf] = __builtin_amdgcn_mfma_f32_16x16x32_f16(ai1, br, acci[1][nf], 0, 0, 0);
        }
    }
    int rg = (lane >> 4) * 4;
    #pragma unroll
    for (int mf = 0; mf < 2; ++mf)
        #pragma unroll
        for (int nf = 0; nf < 2; ++nf) {
            int co = wn * 32 + nf * 16 + fr;
            #pragma unroll
            for (int r = 0; r < 4; ++r) {
                int mp = mt * 64 + wm * 32 + mf * 16 + rg + r;
                if (mp < 255) {
                    Or[(size_t)mp * 8192 + l * 64 + co] = (f16)accr[mf][nf][r];
                    Oi[(size_t)mp * 8192 + l * 64 + co] = (f16)acci[mf][nf][r];
                }
            }
        }
}

// ---------------- K_g4: stage 4 MFMA (64-tile, round-4 form) ----------------
__global__ __launch_bounds__(256) void k_g4(const f16* __restrict__ legT, const f16* __restrict__ OTr,
        const f16* __restrict__ OTi, f16* __restrict__ G) {
    __shared__ f16 As[64][40], Br[64][40], Bi[64][40];
    int mp = blockIdx.x, tt = blockIdx.y, tid = threadIdx.x;
    int mmv = mp - 127, am = mmv < 0 ? -mmv : mmv;
    const f16* A  = legT + (size_t)am * (256 * 128) + (size_t)(tt * 64) * 128;
    const f16* B0 = OTr + (size_t)mp * (64 * 128);
    const f16* B1 = OTi + (size_t)mp * (64 * 128);
    f32x4 acc[2][2][2];
    #pragma unroll
    for (int a = 0; a < 2; ++a)
        #pragma unroll
        for (int b = 0; b < 2; ++b)
            #pragma unroll
            for (int c = 0; c < 2; ++c) acc[a][b][c] = (f32x4){0.f, 0.f, 0.f, 0.f};
    int lane = tid & 63, wid = tid >> 6;
    int wm = wid & 1, wn = wid >> 1;
    int fr = lane & 15, g8 = (lane >> 4) * 8;
    int row = tid >> 2, k8 = (tid & 3) * 8;
    for (int kt = am >> 5; kt < 4; ++kt) {
        float4 va = *(const float4*)(A  + (size_t)row * 128 + kt * 32 + k8);
        float4 vr = *(const float4*)(B0 + (size_t)row * 128 + kt * 32 + k8);
        float4 vi = *(const float4*)(B1 + (size_t)row * 128 + kt * 32 + k8);
        __syncthreads();
        *(float4*)&As[row][k8] = va;
        *(float4*)&Br[row][k8] = vr;
        *(float4*)&Bi[row][k8] = vi;
        __syncthreads();
        f16x8 a0 = *(f16x8*)&As[wm * 32 + fr][g8];
        f16x8 a1 = *(f16x8*)&As[wm * 32 + 16 + fr][g8];
        f16x8 r0 = *(f16x8*)&Br[wn * 32 + fr][g8];
        f16x8 r1 = *(f16x8*)&Br[wn * 32 + 16 + fr][g8];
        f16x8 i0 = *(f16x8*)&Bi[wn * 32 + fr][g8];
        f16x8 i1 = *(f16x8*)&Bi[wn * 32 + 16 + fr][g8];
        acc[0][0][0] = __builtin_amdgcn_mfma_f32_16x16x32_f16(a0, r0, acc[0][0][0], 0, 0, 0);
        acc[0][0][1] = __builtin_amdgcn_mfma_f32_16x16x32_f16(a0, r1, acc[0][0][1], 0, 0, 0);
        acc[0][1][0] = __builtin_amdgcn_mfma_f32_16x16x32_f16(a1, r0, acc[0][1][0], 0, 0, 0);
        acc[0][1][1] = __builtin_amdgcn_mfma_f32_16x16x32_f16(a1, r1, acc[0][1][1], 0, 0, 0);
        acc[1][0][0] = __builtin_amdgcn_mfma_f32_16x16x32_f16(a0, i0, acc[1][0][0], 0, 0, 0);
        acc[1][0][1] = __builtin_amdgcn_mfma_f32_16x16x32_f16(a0, i1, acc[1][0][1], 0, 0, 0);
        acc[1][1][0] = __builtin_amdgcn_mfma_f32_16x16x32_f16(a1, i0, acc[1][1][0], 0, 0, 0);
        acc[1][1][1] = __builtin_amdgcn_mfma_f32_16x16x32_f16(a1, i1, acc[1][1][1], 0, 0, 0);
    }
    int rg = (lane >> 4) * 4;
    f16* gr = G + (size_t)(2 * mp) * (256 * 64);
    f16* gi = G + (size_t)(2 * mp + 1) * (256 * 64);
    #pragma unroll
    for (int mf = 0; mf < 2; ++mf)
        #pragma unroll
        for (int nf = 0; nf < 2; ++nf) {
            int c = wn * 32 + nf * 16 + fr;
            #pragma unroll
            for (int r = 0; r < 4; ++r) {
                int tl = tt * 64 + wm * 32 + mf * 16 + rg + r;
                gr[(size_t)tl * 64 + c] = (f16)acc[0][mf][nf][r];
                gi[(size_t)tl * 64 + c] = (f16)acc[1][mf][nf][r];
            }
        }
}

// ---------------- K_g5: stage 5 MFMA (64-tile, round-4 form) ----------------
__global__ __launch_bounds__(256) void k_g5(const f16* __restrict__ A5, const f16* __restrict__ GT,
                                            float* __restrict__ out) {
    __shared__ f16 As[64][40], Bs[64][40];
    int t = blockIdx.x, pt = blockIdx.y, tid = threadIdx.x;
    const f16* A = A5 + (size_t)(pt * 64) * 512;
    const f16* B = GT + (size_t)t * (64 * 512);
    f32x4 acc[2][2];
    #pragma unroll
    for (int a = 0; a < 2; ++a)
        #pragma unroll
        for (int b = 0; b < 2; ++b) acc[a][b] = (f32x4){0.f, 0.f, 0.f, 0.f};
    int lane = tid & 63, wid = tid >> 6;
    int wm = wid & 1, wn = wid >> 1;
    int fr = lane & 15, g8 = (lane >> 4) * 8;
    int row = tid >> 2, k8 = (tid & 3) * 8;
    for (int kt = 0; kt < 16; ++kt) {
        float4 va = *(const float4*)(A + (size_t)row * 512 + kt * 32 + k8);
        float4 vb = *(const float4*)(B + (size_t)row * 512 + kt * 32 + k8);
        __syncthreads();
        *(float4*)&As[row][k8] = va;
        *(float4*)&Bs[row][k8] = vb;
        __syncthreads();
        f16x8 a0 = *(f16x8*)&As[wm * 32 + fr][g8];
        f16x8 a1 = *(f16x8*)&As[wm * 32 + 16 + fr][g8];
        f16x8 b0 = *(f16x8*)&Bs[wn * 32 + fr][g8];
        f16x8 b1 = *(f16x8*)&Bs[wn * 32 + 16 + fr][g8];
        acc[0][0] = __builtin_amdgcn_mfma_f32_16x16x32_f16(a0, b0, acc[0][0], 0, 0, 0);
        acc[0][1] = __builtin_amdgcn_mfma_f32_16x16x32_f16(a0, b1, acc[0][1], 0, 0, 0);
        acc[1][0] = __builtin_amdgcn_mfma_f32_16x16x32_f16(a1, b0, acc[1][0], 0, 0, 0);
        acc[1][1] = __builtin_amdgcn_mfma_f32_16x16x32_f16(a1, b1, acc[1][1], 0, 0, 0);
    }
    int rg = (lane >> 4) * 4;
    #pragma unroll
    for (int mf = 0; mf < 2; ++mf)
        #pragma unroll
        for (int nf = 0; nf < 2; ++nf) {
            int c = wn * 32 + nf * 16 + fr;
            #pragma unroll
            for (int r = 0; r < 4; ++r) {
                int p = pt * 64 + wm * 32 + mf * 16 + rg + r;
                if (p < NPHI) out[((size_t)t * NPHI + p) * 64 + c] = acc[mf][nf][r];
            }
        }
}

extern "C" void kernel_launch(void* const* d_in, const int* in_sizes, int n_in,
                              void* d_out, int out_size, void* d_ws, size_t ws_size,
                              hipStream_t stream) {
    const float* x    = (const float*)d_in[0];
    const float* temb = (const float*)d_in[1];
    const float* Ar   = (const float*)d_in[2];
    const float* Ai   = (const float*)d_in[3];
    const float* Rr   = (const float*)d_in[4];
    const float* Ri   = (const float*)d_in[5];
    float* out = (float*)d_out;

    char* ws = (char*)d_ws;
    size_t off = 0;
    auto alloc = [&](size_t bytes) -> void* {
        void* p = ws + off;
        off = (off + bytes + 255) & ~(size_t)255;
        return p;
    };
    double* w64  = (double*)alloc(256 * 8);
    f16* legh   = (f16*)alloc((size_t)128 * 128 * 256 * 2);   // 8.39 MB
    f16* leghT  = (f16*)alloc((size_t)128 * 256 * 128 * 2);   // 8.39 MB
    f16* CS     = (f16*)alloc((size_t)2 * 128 * 512 * 2);     // 256 KB (cF | sF)
    f16* A5     = (f16*)alloc((size_t)512 * 512 * 2);         // 512 KB
    f16* Rphr   = (f16*)alloc((size_t)128 * 64 * 64 * 2);     // 1.05 MB
    f16* Rphi   = (f16*)alloc((size_t)128 * 64 * 64 * 2);
    f16* R1     = (f16*)alloc((size_t)256 * 64 * 512 * 2);    // 16.78 MB: xh -> GT
    f16* R2     = (f16*)alloc((size_t)512 * 256 * 64 * 2);    // 16.78 MB: Fw{R,I,RT,IT} -> Gk
    f16* Xhr    = (f16*)alloc((size_t)128 * 128 * 64 * 2);    // 2.1 MB
    f16* Xhi    = (f16*)alloc((size_t)128 * 128 * 64 * 2);
    f16* Or     = (f16*)alloc((size_t)255 * 128 * 64 * 2);    // 4.18 MB
    f16* Oi     = (f16*)alloc((size_t)255 * 128 * 64 * 2);
    f16* OrT    = (f16*)alloc((size_t)255 * 64 * 128 * 2);
    f16* OiT    = (f16*)alloc((size_t)255 * 64 * 128 * 2);
    if (off > ws_size) return;

    f16* xh   = R1;
    f16* GT   = R1;
    f16* FwR  = R2;
    f16* FwI  = R2 + (size_t)2097152;
    f16* FwRT = R2 + (size_t)4194304;
    f16* FwIT = R2 + (size_t)6291456;
    f16* Gk   = R2;   // rows 510,511 stale-but-finite; A5 cols 510,511 == 0
    f16* cF   = CS;
    f16* sF   = CS + (size_t)65536;

    hipLaunchKernelGGL(k_leg,      dim3(128),        dim3(256), 0, stream, legh, leghT, w64);
    hipLaunchKernelGGL(k_tables_h, dim3(1024),       dim3(256), 0, stream, CS, A5);
    hipLaunchKernelGGL(k_prep_R,   dim3(128),        dim3(256), 0, stream, Rr, Ri, Ar, Ai, temb, Rphr, Rphi);
    hipLaunchKernelGGL(k_convert,  dim3(256, 8),     dim3(256), 0, stream, x, xh);
    hipLaunchKernelGGL(k_g1,       dim3(256, 2),     dim3(256), 0, stream, xh, cF, sF, w64, FwR, FwI);
    hipLaunchKernelGGL(k_trp,      dim3(128, 4, 2),  dim3(256), 0, stream, FwR, FwRT, FwI, FwIT, 256, 64, 16384, 16384);
    hipLaunchKernelGGL(k_g2,       dim3(128, 2),     dim3(256), 0, stream, legh, FwRT, FwIT, Xhr, Xhi);
    hipLaunchKernelGGL(k_s3m,      dim3(128, 4),     dim3(256), 0, stream, Xhr, Xhi, Rphr, Rphi, Or, Oi);
    hipLaunchKernelGGL(k_trp,      dim3(255, 2, 2),  dim3(256), 0, stream, Or, OrT, Oi, OiT, 128, 64, 8192, 8192);
    hipLaunchKernelGGL(k_g4,       dim3(255, 4),     dim3(256), 0, stream, leghT, OrT, OiT, Gk);
    hipLaunchKernelGGL(k_tr16,     dim3(1, 2048),    dim3(256), 0, stream, Gk, GT, 512, 16384);
    hipLaunchKernelGGL(k_g5,       dim3(256, 8),     dim3(256), 0, stream, A5, GT, out);
}